// Round 1
// baseline (152.934 us; speedup 1.0000x reference)
//
#include <hip/hip_runtime.h>
#include <hip/hip_bf16.h>

using f32x4  = __attribute__((ext_vector_type(4))) float;
using bf16x8 = __attribute__((ext_vector_type(8))) short;

// Device-global scratch (avoids any ws_size assumption); fully rewritten every call.
__device__ __attribute__((aligned(16))) unsigned short g_Abf[64 * 64]; // bf16 bits of A = Re(U^H D U), symmetric
__device__ float2 g_U[64 * 64];                                        // U[i][t] row-major
__device__ float  g_A00;                                               // fallback value for zero-norm rows

__device__ inline unsigned short f2bf(float x) { // fp32 -> bf16 RNE
  unsigned u = __builtin_bit_cast(unsigned, x);
  return (unsigned short)((u + 0x7FFFu + ((u >> 16) & 1u)) >> 16);
}
__device__ inline float2 cmul(float2 a, float2 b) {
  return make_float2(a.x * b.x - a.y * b.y, a.x * b.y + a.y * b.x);
}
__device__ inline float2 cadd(float2 a, float2 b) { return make_float2(a.x + b.x, a.y + b.y); }

// ---------------- circuit simulation: psi[i*64+t] = amp i of column t ----------------
__device__ inline void gate1q(float2* psi, int t, int sub, int q,
                              float2 u00, float2 u01, float2 u10, float2 u11) {
  const int bit = 1 << q, mask = bit - 1;
#pragma unroll
  for (int pp = 0; pp < 8; ++pp) {
    int p  = sub * 8 + pp;                     // 32 pairs split over 4 sub-threads
    int i0 = ((p & ~mask) << 1) | (p & mask);  // insert 0 at bit q
    int i1 = i0 | bit;
    float2 a0 = psi[i0 * 64 + t], a1 = psi[i1 * 64 + t];
    psi[i0 * 64 + t] = cadd(cmul(u00, a0), cmul(u01, a1));
    psi[i1 * 64 + t] = cadd(cmul(u10, a0), cmul(u11, a1));
  }
}

__device__ inline void gatec(float2* psi, int t, int sub, int c, int g,
                             float2 v00, float2 v01, float2 v10, float2 v11) {
  const int cb = 1 << c, gb = 1 << g;
  const int lo = (c < g ? c : g), hi = (c < g ? g : c);
  const int mlo = (1 << lo) - 1, mhi = (1 << hi) - 1;
#pragma unroll
  for (int pp = 0; pp < 4; ++pp) {
    int p = sub * 4 + pp;                      // 16 pairs split over 4 sub-threads
    int y = ((p & ~mlo) << 1) | (p & mlo);     // insert 0 at lo
    y     = ((y & ~mhi) << 1) | (y & mhi);     // insert 0 at hi
    int i0 = y | cb;                           // control=1, target=0
    int i1 = i0 | gb;
    float2 a0 = psi[i0 * 64 + t], a1 = psi[i1 * 64 + t];
    psi[i0 * 64 + t] = cadd(cmul(v00, a0), cmul(v01, a1));
    psi[i1 * 64 + t] = cadd(cmul(v10, a0), cmul(v11, a1));
  }
}

__device__ inline void u3mat(float th, float ph, float la,
                             float2& u00, float2& u01, float2& u10, float2& u11) {
  float s, c;  sincosf(0.5f * th, &s, &c);
  float sp, cp; sincosf(ph, &sp, &cp);
  float sl, cl; sincosf(la, &sl, &cl);
  u00 = make_float2(c, 0.f);
  u01 = make_float2(-cl * s, -sl * s);
  u10 = make_float2(cp * s, sp * s);
  u11 = make_float2((cp * cl - sp * sl) * c, (cp * sl + sp * cl) * c);
}

__global__ __launch_bounds__(256) void sim_kernel(const float* __restrict__ P) {
  __shared__ float2 psi[64 * 64];
  const int t = threadIdx.x & 63, sub = threadIdx.x >> 6;
  for (int idx = threadIdx.x; idx < 4096; idx += 256)
    psi[idx] = make_float2(((idx >> 6) == (idx & 63)) ? 1.f : 0.f, 0.f);
  __syncthreads();
  float2 u00, u01, u10, u11;
  const float2 Z = make_float2(0.f, 0.f), ONE = make_float2(1.f, 0.f);
  // layer 1: U3 on all qubits (params 0..17)
#pragma unroll
  for (int q = 0; q < 6; ++q) {
    u3mat(P[3 * q], P[3 * q + 1], P[3 * q + 2], u00, u01, u10, u11);
    gate1q(psi, t, sub, q, u00, u01, u10, u11);
    __syncthreads();
  }
  gatec(psi, t, sub, 2, 1, Z, ONE, ONE, Z); __syncthreads();               // CX c2 t1
  { float sl, cl; sincosf(P[18], &sl, &cl);
    gate1q(psi, t, sub, 1, ONE, Z, Z, make_float2(cl, sl)); __syncthreads(); } // P on 1
  gatec(psi, t, sub, 4, 3, Z, ONE, ONE, Z); __syncthreads();               // CX c4 t3
  { float sl, cl; sincosf(P[19], &sl, &cl);
    gate1q(psi, t, sub, 3, ONE, Z, Z, make_float2(cl, sl)); __syncthreads(); } // P on 3
  // layer 2: U3 on {0,1,3,5} (params 20..31)
  const int qs[4] = {0, 1, 3, 5};
#pragma unroll
  for (int ii = 0; ii < 4; ++ii) {
    u3mat(P[20 + 3 * ii], P[21 + 3 * ii], P[22 + 3 * ii], u00, u01, u10, u11);
    gate1q(psi, t, sub, qs[ii], u00, u01, u10, u11);
    __syncthreads();
  }
  u3mat(P[32], P[33], P[34], u00, u01, u10, u11); gatec(psi, t, sub, 0, 1, u00, u01, u10, u11); __syncthreads();
  u3mat(P[35], P[36], P[37], u00, u01, u10, u11); gatec(psi, t, sub, 3, 5, u00, u01, u10, u11); __syncthreads();
  gatec(psi, t, sub, 3, 1, Z, ONE, ONE, Z); __syncthreads();               // CX c3 t1
  { float sl, cl; sincosf(P[38], &sl, &cl);
    gate1q(psi, t, sub, 1, ONE, Z, Z, make_float2(cl, sl)); __syncthreads(); } // P on 1
  u3mat(P[39], P[40], P[41], u00, u01, u10, u11); gate1q(psi, t, sub, 0, u00, u01, u10, u11); __syncthreads();
  u3mat(P[42], P[43], P[44], u00, u01, u10, u11); gate1q(psi, t, sub, 1, u00, u01, u10, u11); __syncthreads();
  u3mat(P[45], P[46], P[47], u00, u01, u10, u11); gatec(psi, t, sub, 0, 1, u00, u01, u10, u11); __syncthreads();
  u3mat(P[48], P[49], P[50], u00, u01, u10, u11); gate1q(psi, t, sub, 0, u00, u01, u10, u11); __syncthreads();
  u3mat(P[51], P[52], P[53], u00, u01, u10, u11); gate1q(psi, t, sub, 1, u00, u01, u10, u11); __syncthreads();
  for (int idx = threadIdx.x; idx < 4096; idx += 256) g_U[idx] = psi[idx];
}

// ---------------- A[j][k] = Re sum_i sign(i) conj(U[i][j]) U[i][k] ----------------
__global__ __launch_bounds__(256) void amat_kernel() {
  const int idx = blockIdx.x * 256 + threadIdx.x; // 0..4095
  const int j = idx >> 6, k = idx & 63;
  float s = 0.f;
#pragma unroll 8
  for (int i = 0; i < 64; ++i) {
    float2 uj = g_U[i * 64 + j], uk = g_U[i * 64 + k];
    float d = uj.x * uk.x + uj.y * uk.y;
    s += (i < 32) ? d : -d;
  }
  g_Abf[idx] = f2bf(s); // symmetric by construction (identical fp32 op order)
  if (idx == 0) g_A00 = s;
}

// ---------------- out[b] = (f^T A f) / (f^T f), MFMA 16x16x32 bf16 ----------------
#define MFMA(A, B, C) __builtin_amdgcn_mfma_f32_16x16x32_bf16(A, B, C, 0, 0, 0)

__global__ __launch_bounds__(256) void qexp_kernel(const float* __restrict__ F, float* __restrict__ out) {
  __shared__ float flds[4][16 * 68]; // wave-private fp32 F tiles, pad 68 vs bank conflicts
  const int lane = threadIdx.x & 63;
  const int wid  = threadIdx.x >> 6;
  const int g = lane >> 4, c0 = lane & 15;
  float* fl = flds[wid];

  // B fragments: B[k][n], n = lane%16, k = 8*(lane/16)+i (+ks*32). A symmetric ->
  // read Abf[n*64 + k] : 16 contiguous bytes per fragment.
  const unsigned short* ab = g_Abf + (unsigned)(c0 * 64 + g * 8);
  const bf16x8 b00 = *(const bf16x8*)(ab);
  const bf16x8 b01 = *(const bf16x8*)(ab + 32);
  const bf16x8 b10 = *(const bf16x8*)(ab + 16 * 64);
  const bf16x8 b11 = *(const bf16x8*)(ab + 16 * 64 + 32);
  const bf16x8 b20 = *(const bf16x8*)(ab + 32 * 64);
  const bf16x8 b21 = *(const bf16x8*)(ab + 32 * 64 + 32);
  const bf16x8 b30 = *(const bf16x8*)(ab + 48 * 64);
  const bf16x8 b31 = *(const bf16x8*)(ab + 48 * 64 + 32);
  const float A00 = g_A00;

  const int nwaves = gridDim.x << 2;
  for (int tile = (int)(blockIdx.x << 2) | wid; tile < 16384; tile += nwaves) {
    const int b0 = tile << 4;
    // A fragment: row m = lane%16 = c0, k = 8*(lane/16)+i (+32 for second K-step)
    const float* fr = F + (size_t)(b0 + c0) * 64 + g * 8;
    const float4 v0 = *(const float4*)(fr);
    const float4 v1 = *(const float4*)(fr + 4);
    const float4 v2 = *(const float4*)(fr + 32);
    const float4 v3 = *(const float4*)(fr + 36);
    bf16x8 a0, a1;
    a0[0] = f2bf(v0.x); a0[1] = f2bf(v0.y); a0[2] = f2bf(v0.z); a0[3] = f2bf(v0.w);
    a0[4] = f2bf(v1.x); a0[5] = f2bf(v1.y); a0[6] = f2bf(v1.z); a0[7] = f2bf(v1.w);
    a1[0] = f2bf(v2.x); a1[1] = f2bf(v2.y); a1[2] = f2bf(v2.z); a1[3] = f2bf(v2.w);
    a1[4] = f2bf(v3.x); a1[5] = f2bf(v3.y); a1[6] = f2bf(v3.z); a1[7] = f2bf(v3.w);
    float* fw = fl + c0 * 68 + g * 8; // keep fp32 copy for the epilogue dot / norm
    *(float4*)(fw)      = v0;
    *(float4*)(fw + 4)  = v1;
    *(float4*)(fw + 32) = v2;
    *(float4*)(fw + 36) = v3;

    f32x4 acc0 = {0.f, 0.f, 0.f, 0.f}, acc1 = acc0, acc2 = acc0, acc3 = acc0;
    acc0 = MFMA(a0, b00, acc0); acc0 = MFMA(a1, b01, acc0);
    acc1 = MFMA(a0, b10, acc1); acc1 = MFMA(a1, b11, acc1);
    acc2 = MFMA(a0, b20, acc2); acc2 = MFMA(a1, b21, acc2);
    acc3 = MFMA(a0, b30, acc3); acc3 = MFMA(a1, b31, acc3);

    asm volatile("s_waitcnt lgkmcnt(0)" ::: "memory"); // wave-private LDS: writes -> reads
    // C layout: row = 4*(lane>>4)+reg, col = nt*16 + (lane&15)
    float num0 = 0, num1 = 0, num2 = 0, num3 = 0, den0 = 0, den1 = 0, den2 = 0, den3 = 0;
    const float* fb = fl + g * 4 * 68 + c0;
#define EPI(ACC, NT) { \
    float fv0 = fb[(NT) * 16];          num0 = fmaf(ACC[0], fv0, num0); den0 = fmaf(fv0, fv0, den0); \
    float fv1 = fb[68 + (NT) * 16];     num1 = fmaf(ACC[1], fv1, num1); den1 = fmaf(fv1, fv1, den1); \
    float fv2 = fb[2 * 68 + (NT) * 16]; num2 = fmaf(ACC[2], fv2, num2); den2 = fmaf(fv2, fv2, den2); \
    float fv3 = fb[3 * 68 + (NT) * 16]; num3 = fmaf(ACC[3], fv3, num3); den3 = fmaf(fv3, fv3, den3); }
    EPI(acc0, 0) EPI(acc1, 1) EPI(acc2, 2) EPI(acc3, 3)
#undef EPI
#pragma unroll
    for (int m = 1; m < 16; m <<= 1) { // reduce over the 16 lanes of each group
      num0 += __shfl_xor(num0, m, 64); den0 += __shfl_xor(den0, m, 64);
      num1 += __shfl_xor(num1, m, 64); den1 += __shfl_xor(den1, m, 64);
      num2 += __shfl_xor(num2, m, 64); den2 += __shfl_xor(den2, m, 64);
      num3 += __shfl_xor(num3, m, 64); den3 += __shfl_xor(den3, m, 64);
    }
    if (c0 < 4) {
      float nv = (c0 == 0) ? num0 : (c0 == 1) ? num1 : (c0 == 2) ? num2 : num3;
      float dv = (c0 == 0) ? den0 : (c0 == 1) ? den1 : (c0 == 2) ? den2 : den3;
      out[b0 + g * 4 + c0] = (dv <= 1e-16f) ? A00 : nv / dv; // isclose(norm,0) -> |0> fallback
    }
  }
}

extern "C" void kernel_launch(void* const* d_in, const int* in_sizes, int n_in,
                              void* d_out, int out_size, void* d_ws, size_t ws_size,
                              hipStream_t stream) {
  const float* F = (const float*)d_in[0]; // (262144, 64) fp32
  const float* P = (const float*)d_in[1]; // (54,) fp32
  float* out = (float*)d_out;             // (262144,) fp32
  sim_kernel<<<1, 256, 0, stream>>>(P);
  amat_kernel<<<16, 256, 0, stream>>>();
  qexp_kernel<<<2048, 256, 0, stream>>>(F, out);
}

// Round 2
// 121.418 us; speedup vs baseline: 1.2596x; 1.2596x over previous
//
#include <hip/hip_runtime.h>
#include <hip/hip_bf16.h>

using f32x4  = __attribute__((ext_vector_type(4))) float;
using bf16x8 = __attribute__((ext_vector_type(8))) short;

// Device-global scratch (avoids any ws_size assumption); fully rewritten every call.
__device__ __attribute__((aligned(16))) unsigned short g_Abf[64 * 64]; // bf16 bits of A = Re(U^H D U), symmetric
__device__ float2 g_U[64 * 64];                                        // U[i][t] row-major
__device__ float  g_A00;                                               // fallback value for zero-norm rows

__device__ inline unsigned short f2bf(float x) { // fp32 -> bf16 RNE
  unsigned u = __builtin_bit_cast(unsigned, x);
  return (unsigned short)((u + 0x7FFFu + ((u >> 16) & 1u)) >> 16);
}
__device__ inline float2 cmul(float2 a, float2 b) {
  return make_float2(a.x * b.x - a.y * b.y, a.x * b.y + a.y * b.x);
}
__device__ inline float2 cadd(float2 a, float2 b) { return make_float2(a.x + b.x, a.y + b.y); }

// ---------------- circuit simulation: psi[i*64+t] = amp i of column t ----------------
__device__ inline void gate1q(float2* psi, int t, int sub, int q,
                              float2 u00, float2 u01, float2 u10, float2 u11) {
  const int bit = 1 << q, mask = bit - 1;
#pragma unroll
  for (int pp = 0; pp < 8; ++pp) {
    int p  = sub * 8 + pp;                     // 32 pairs split over 4 sub-threads
    int i0 = ((p & ~mask) << 1) | (p & mask);  // insert 0 at bit q
    int i1 = i0 | bit;
    float2 a0 = psi[i0 * 64 + t], a1 = psi[i1 * 64 + t];
    psi[i0 * 64 + t] = cadd(cmul(u00, a0), cmul(u01, a1));
    psi[i1 * 64 + t] = cadd(cmul(u10, a0), cmul(u11, a1));
  }
}

__device__ inline void gatec(float2* psi, int t, int sub, int c, int g,
                             float2 v00, float2 v01, float2 v10, float2 v11) {
  const int cb = 1 << c, gb = 1 << g;
  const int lo = (c < g ? c : g), hi = (c < g ? g : c);
  const int mlo = (1 << lo) - 1, mhi = (1 << hi) - 1;
#pragma unroll
  for (int pp = 0; pp < 4; ++pp) {
    int p = sub * 4 + pp;                      // 16 pairs split over 4 sub-threads
    int y = ((p & ~mlo) << 1) | (p & mlo);     // insert 0 at lo
    y     = ((y & ~mhi) << 1) | (y & mhi);     // insert 0 at hi
    int i0 = y | cb;                           // control=1, target=0
    int i1 = i0 | gb;
    float2 a0 = psi[i0 * 64 + t], a1 = psi[i1 * 64 + t];
    psi[i0 * 64 + t] = cadd(cmul(v00, a0), cmul(v01, a1));
    psi[i1 * 64 + t] = cadd(cmul(v10, a0), cmul(v11, a1));
  }
}

__global__ __launch_bounds__(256) void sim_kernel(const float* __restrict__ P) {
  __shared__ float2 psi[64 * 64];
  // Parallel trig precompute: kills the serial sincosf libcall chain (was 134 us:
  // per-thread serial chain of ~58 ocml sincosf scratch round-trips, VALUBusy 0.02%).
  __shared__ float tS[54], tC[54], tSh[54], tCh[54];
  const int t = threadIdx.x & 63, sub = threadIdx.x >> 6;
  if (threadIdx.x < 54) {
    float p = P[threadIdx.x];
    tS[threadIdx.x]  = __sinf(p);          // hardware v_sin_f32 path, args < 0.32
    tC[threadIdx.x]  = __cosf(p);
    tSh[threadIdx.x] = __sinf(0.5f * p);
    tCh[threadIdx.x] = __cosf(0.5f * p);
  }
  for (int idx = threadIdx.x; idx < 4096; idx += 256)
    psi[idx] = make_float2(((idx >> 6) == (idx & 63)) ? 1.f : 0.f, 0.f);
  __syncthreads();

  float2 u00, u01, u10, u11;
  const float2 Z = make_float2(0.f, 0.f), ONE = make_float2(1.f, 0.f);
  auto U3L = [&](int i) { // qiskit U(theta,phi,lam) from LDS trig tables
    float ch = tCh[i], sh = tSh[i];
    float cp = tC[i + 1], sp = tS[i + 1];
    float cl = tC[i + 2], sl = tS[i + 2];
    u00 = make_float2(ch, 0.f);
    u01 = make_float2(-cl * sh, -sl * sh);
    u10 = make_float2(cp * sh, sp * sh);
    u11 = make_float2((cp * cl - sp * sl) * ch, (cp * sl + sp * cl) * ch);
  };
  auto PH = [&](int i) { return make_float2(tC[i], tS[i]); };

  // layer 1: U3 on all qubits (params 0..17)
#pragma unroll
  for (int q = 0; q < 6; ++q) {
    U3L(3 * q);
    gate1q(psi, t, sub, q, u00, u01, u10, u11);
    __syncthreads();
  }
  gatec(psi, t, sub, 2, 1, Z, ONE, ONE, Z); __syncthreads();                  // CX c2 t1
  gate1q(psi, t, sub, 1, ONE, Z, Z, PH(18)); __syncthreads();                 // P on 1
  gatec(psi, t, sub, 4, 3, Z, ONE, ONE, Z); __syncthreads();                  // CX c4 t3
  gate1q(psi, t, sub, 3, ONE, Z, Z, PH(19)); __syncthreads();                 // P on 3
  // layer 2: U3 on {0,1,3,5} (params 20..31)
  const int qs[4] = {0, 1, 3, 5};
#pragma unroll
  for (int ii = 0; ii < 4; ++ii) {
    U3L(20 + 3 * ii);
    gate1q(psi, t, sub, qs[ii], u00, u01, u10, u11);
    __syncthreads();
  }
  U3L(32); gatec(psi, t, sub, 0, 1, u00, u01, u10, u11); __syncthreads();     // CU c0 t1
  U3L(35); gatec(psi, t, sub, 3, 5, u00, u01, u10, u11); __syncthreads();     // CU c3 t5
  gatec(psi, t, sub, 3, 1, Z, ONE, ONE, Z); __syncthreads();                  // CX c3 t1
  gate1q(psi, t, sub, 1, ONE, Z, Z, PH(38)); __syncthreads();                 // P on 1
  U3L(39); gate1q(psi, t, sub, 0, u00, u01, u10, u11); __syncthreads();
  U3L(42); gate1q(psi, t, sub, 1, u00, u01, u10, u11); __syncthreads();
  U3L(45); gatec(psi, t, sub, 0, 1, u00, u01, u10, u11); __syncthreads();     // CU c0 t1
  U3L(48); gate1q(psi, t, sub, 0, u00, u01, u10, u11); __syncthreads();
  U3L(51); gate1q(psi, t, sub, 1, u00, u01, u10, u11); __syncthreads();
  for (int idx = threadIdx.x; idx < 4096; idx += 256) g_U[idx] = psi[idx];
}

// ---------------- A[j][k] = Re sum_i sign(i) conj(U[i][j]) U[i][k] ----------------
__global__ __launch_bounds__(256) void amat_kernel() {
  const int idx = blockIdx.x * 256 + threadIdx.x; // 0..4095
  const int j = idx >> 6, k = idx & 63;
  float s = 0.f;
#pragma unroll 8
  for (int i = 0; i < 64; ++i) {
    float2 uj = g_U[i * 64 + j], uk = g_U[i * 64 + k];
    float d = uj.x * uk.x + uj.y * uk.y;
    s += (i < 32) ? d : -d;
  }
  g_Abf[idx] = f2bf(s); // symmetric by construction (identical fp32 op order)
  if (idx == 0) g_A00 = s;
}

// ---------------- out[b] = (f^T A f) / (f^T f), MFMA 16x16x32 bf16 ----------------
#define MFMA(A, B, C) __builtin_amdgcn_mfma_f32_16x16x32_bf16(A, B, C, 0, 0, 0)

__global__ __launch_bounds__(256) void qexp_kernel(const float* __restrict__ F, float* __restrict__ out) {
  __shared__ float flds[4][16 * 68]; // wave-private fp32 F tiles, pad 68 vs bank conflicts
  const int lane = threadIdx.x & 63;
  const int wid  = threadIdx.x >> 6;
  const int g = lane >> 4, c0 = lane & 15;
  float* fl = flds[wid];

  // B fragments: B[k][n], n = lane%16, k = 8*(lane/16)+i (+ks*32). A symmetric ->
  // read Abf[n*64 + k] : 16 contiguous bytes per fragment.
  const unsigned short* ab = g_Abf + (unsigned)(c0 * 64 + g * 8);
  const bf16x8 b00 = *(const bf16x8*)(ab);
  const bf16x8 b01 = *(const bf16x8*)(ab + 32);
  const bf16x8 b10 = *(const bf16x8*)(ab + 16 * 64);
  const bf16x8 b11 = *(const bf16x8*)(ab + 16 * 64 + 32);
  const bf16x8 b20 = *(const bf16x8*)(ab + 32 * 64);
  const bf16x8 b21 = *(const bf16x8*)(ab + 32 * 64 + 32);
  const bf16x8 b30 = *(const bf16x8*)(ab + 48 * 64);
  const bf16x8 b31 = *(const bf16x8*)(ab + 48 * 64 + 32);
  const float A00 = g_A00;

  const int nwaves = gridDim.x << 2;
  for (int tile = (int)(blockIdx.x << 2) | wid; tile < 16384; tile += nwaves) {
    const int b0 = tile << 4;
    // A fragment: row m = lane%16 = c0, k = 8*(lane/16)+i (+32 for second K-step)
    const float* fr = F + (size_t)(b0 + c0) * 64 + g * 8;
    const float4 v0 = *(const float4*)(fr);
    const float4 v1 = *(const float4*)(fr + 4);
    const float4 v2 = *(const float4*)(fr + 32);
    const float4 v3 = *(const float4*)(fr + 36);
    bf16x8 a0, a1;
    a0[0] = f2bf(v0.x); a0[1] = f2bf(v0.y); a0[2] = f2bf(v0.z); a0[3] = f2bf(v0.w);
    a0[4] = f2bf(v1.x); a0[5] = f2bf(v1.y); a0[6] = f2bf(v1.z); a0[7] = f2bf(v1.w);
    a1[0] = f2bf(v2.x); a1[1] = f2bf(v2.y); a1[2] = f2bf(v2.z); a1[3] = f2bf(v2.w);
    a1[4] = f2bf(v3.x); a1[5] = f2bf(v3.y); a1[6] = f2bf(v3.z); a1[7] = f2bf(v3.w);
    float* fw = fl + c0 * 68 + g * 8; // keep fp32 copy for the epilogue dot / norm
    *(float4*)(fw)      = v0;
    *(float4*)(fw + 4)  = v1;
    *(float4*)(fw + 32) = v2;
    *(float4*)(fw + 36) = v3;

    f32x4 acc0 = {0.f, 0.f, 0.f, 0.f}, acc1 = acc0, acc2 = acc0, acc3 = acc0;
    acc0 = MFMA(a0, b00, acc0); acc0 = MFMA(a1, b01, acc0);
    acc1 = MFMA(a0, b10, acc1); acc1 = MFMA(a1, b11, acc1);
    acc2 = MFMA(a0, b20, acc2); acc2 = MFMA(a1, b21, acc2);
    acc3 = MFMA(a0, b30, acc3); acc3 = MFMA(a1, b31, acc3);

    asm volatile("s_waitcnt lgkmcnt(0)" ::: "memory"); // wave-private LDS: writes -> reads
    // C layout: row = 4*(lane>>4)+reg, col = nt*16 + (lane&15)
    float num0 = 0, num1 = 0, num2 = 0, num3 = 0, den0 = 0, den1 = 0, den2 = 0, den3 = 0;
    const float* fb = fl + g * 4 * 68 + c0;
#define EPI(ACC, NT) { \
    float fv0 = fb[(NT) * 16];          num0 = fmaf(ACC[0], fv0, num0); den0 = fmaf(fv0, fv0, den0); \
    float fv1 = fb[68 + (NT) * 16];     num1 = fmaf(ACC[1], fv1, num1); den1 = fmaf(fv1, fv1, den1); \
    float fv2 = fb[2 * 68 + (NT) * 16]; num2 = fmaf(ACC[2], fv2, num2); den2 = fmaf(fv2, fv2, den2); \
    float fv3 = fb[3 * 68 + (NT) * 16]; num3 = fmaf(ACC[3], fv3, num3); den3 = fmaf(fv3, fv3, den3); }
    EPI(acc0, 0) EPI(acc1, 1) EPI(acc2, 2) EPI(acc3, 3)
#undef EPI
#pragma unroll
    for (int m = 1; m < 16; m <<= 1) { // reduce over the 16 lanes of each group
      num0 += __shfl_xor(num0, m, 64); den0 += __shfl_xor(den0, m, 64);
      num1 += __shfl_xor(num1, m, 64); den1 += __shfl_xor(den1, m, 64);
      num2 += __shfl_xor(num2, m, 64); den2 += __shfl_xor(den2, m, 64);
      num3 += __shfl_xor(num3, m, 64); den3 += __shfl_xor(den3, m, 64);
    }
    if (c0 < 4) {
      float nv = (c0 == 0) ? num0 : (c0 == 1) ? num1 : (c0 == 2) ? num2 : num3;
      float dv = (c0 == 0) ? den0 : (c0 == 1) ? den1 : (c0 == 2) ? den2 : den3;
      out[b0 + g * 4 + c0] = (dv <= 1e-16f) ? A00 : nv / dv; // isclose(norm,0) -> |0> fallback
    }
  }
}

extern "C" void kernel_launch(void* const* d_in, const int* in_sizes, int n_in,
                              void* d_out, int out_size, void* d_ws, size_t ws_size,
                              hipStream_t stream) {
  const float* F = (const float*)d_in[0]; // (262144, 64) fp32
  const float* P = (const float*)d_in[1]; // (54,) fp32
  float* out = (float*)d_out;             // (262144,) fp32
  sim_kernel<<<1, 256, 0, stream>>>(P);
  amat_kernel<<<16, 256, 0, stream>>>();
  qexp_kernel<<<2048, 256, 0, stream>>>(F, out);
}

// Round 3
// 120.046 us; speedup vs baseline: 1.2740x; 1.0114x over previous
//
#include <hip/hip_runtime.h>

using f32x4  = __attribute__((ext_vector_type(4))) float;
using bf16x8 = __attribute__((ext_vector_type(8))) short;

__device__ inline unsigned short f2bf(float x) { // fp32 -> bf16 RNE
  unsigned u = __builtin_bit_cast(unsigned, x);
  return (unsigned short)((u + 0x7FFFu + ((u >> 16) & 1u)) >> 16);
}
__device__ inline float2 cmul(float2 a, float2 b) {
  return make_float2(a.x * b.x - a.y * b.y, a.x * b.y + a.y * b.x);
}
__device__ inline float2 cadd(float2 a, float2 b) { return make_float2(a.x + b.x, a.y + b.y); }

// ---- gate helpers on LDS psi[i*64 + t] (i = amplitude, t = basis column) ----
__device__ inline void gate1q(float2* psi, int t, int sub, int q,
                              float2 u00, float2 u01, float2 u10, float2 u11) {
  const int bit = 1 << q, mask = bit - 1;
#pragma unroll
  for (int pp = 0; pp < 8; ++pp) {
    int p  = sub * 8 + pp;
    int i0 = ((p & ~mask) << 1) | (p & mask);
    int i1 = i0 | bit;
    float2 a0 = psi[i0 * 64 + t], a1 = psi[i1 * 64 + t];
    psi[i0 * 64 + t] = cadd(cmul(u00, a0), cmul(u01, a1));
    psi[i1 * 64 + t] = cadd(cmul(u10, a0), cmul(u11, a1));
  }
}

__device__ inline void gatec(float2* psi, int t, int sub, int c, int g,
                             float2 v00, float2 v01, float2 v10, float2 v11) {
  const int cb = 1 << c, gb = 1 << g;
  const int lo = (c < g ? c : g), hi = (c < g ? g : c);
  const int mlo = (1 << lo) - 1, mhi = (1 << hi) - 1;
#pragma unroll
  for (int pp = 0; pp < 4; ++pp) {
    int p = sub * 4 + pp;
    int y = ((p & ~mlo) << 1) | (p & mlo);
    y     = ((y & ~mhi) << 1) | (y & mhi);
    int i0 = y | cb;
    int i1 = i0 | gb;
    float2 a0 = psi[i0 * 64 + t], a1 = psi[i1 * 64 + t];
    psi[i0 * 64 + t] = cadd(cmul(v00, a0), cmul(v01, a1));
    psi[i1 * 64 + t] = cadd(cmul(v10, a0), cmul(v11, a1));
  }
}

#define MFMA(A, B, C) __builtin_amdgcn_mfma_f32_16x16x32_bf16(A, B, C, 0, 0, 0)

// Fully fused: every block redundantly simulates the 64x64 circuit unitary in
// LDS (~few us, runs in parallel on all CUs at full clock), builds the real
// 128x64 matrix Pm = [ReU(i<32); ImU(i<32); ReU(i>=32); ImU(i>=32)] in bf16,
// hoists its MFMA B-fragments to registers, then streams F:
//   out = (|Pp f|^2 - |Pm f|^2) / (|Pp f|^2 + |Pm f|^2)   (den free: U unitary)
__global__ __launch_bounds__(256) void qfused(const float* __restrict__ F,
                                              const float* __restrict__ Pp,
                                              float* __restrict__ out) {
  __shared__ float2 psi[64 * 64];                                   // 32 KB
  __shared__ __attribute__((aligned(16))) unsigned short Plds[128 * 64]; // 16 KB
  __shared__ float tS[54], tC[54], tSh[54], tCh[54];
  __shared__ float sA00;

  const int tid = threadIdx.x;
  const int t = tid & 63, sub = tid >> 6;

  // ---------- prologue: trig tables + circuit sim (verified in r1/r2) ----------
  if (tid < 54) {
    float p = Pp[tid];
    tS[tid]  = __sinf(p);
    tC[tid]  = __cosf(p);
    tSh[tid] = __sinf(0.5f * p);
    tCh[tid] = __cosf(0.5f * p);
  }
  for (int idx = tid; idx < 4096; idx += 256)
    psi[idx] = make_float2(((idx >> 6) == (idx & 63)) ? 1.f : 0.f, 0.f);
  __syncthreads();

  float2 u00, u01, u10, u11;
  const float2 Z = make_float2(0.f, 0.f), ONE = make_float2(1.f, 0.f);
  auto U3L = [&](int i) {
    float ch = tCh[i], sh = tSh[i];
    float cp = tC[i + 1], sp = tS[i + 1];
    float cl = tC[i + 2], sl = tS[i + 2];
    u00 = make_float2(ch, 0.f);
    u01 = make_float2(-cl * sh, -sl * sh);
    u10 = make_float2(cp * sh, sp * sh);
    u11 = make_float2((cp * cl - sp * sl) * ch, (cp * sl + sp * cl) * ch);
  };
  auto PH = [&](int i) { return make_float2(tC[i], tS[i]); };

#pragma unroll
  for (int q = 0; q < 6; ++q) {
    U3L(3 * q); gate1q(psi, t, sub, q, u00, u01, u10, u11); __syncthreads();
  }
  gatec(psi, t, sub, 2, 1, Z, ONE, ONE, Z); __syncthreads();
  gate1q(psi, t, sub, 1, ONE, Z, Z, PH(18)); __syncthreads();
  gatec(psi, t, sub, 4, 3, Z, ONE, ONE, Z); __syncthreads();
  gate1q(psi, t, sub, 3, ONE, Z, Z, PH(19)); __syncthreads();
  const int qs[4] = {0, 1, 3, 5};
#pragma unroll
  for (int ii = 0; ii < 4; ++ii) {
    U3L(20 + 3 * ii); gate1q(psi, t, sub, qs[ii], u00, u01, u10, u11); __syncthreads();
  }
  U3L(32); gatec(psi, t, sub, 0, 1, u00, u01, u10, u11); __syncthreads();
  U3L(35); gatec(psi, t, sub, 3, 5, u00, u01, u10, u11); __syncthreads();
  gatec(psi, t, sub, 3, 1, Z, ONE, ONE, Z); __syncthreads();
  gate1q(psi, t, sub, 1, ONE, Z, Z, PH(38)); __syncthreads();
  U3L(39); gate1q(psi, t, sub, 0, u00, u01, u10, u11); __syncthreads();
  U3L(42); gate1q(psi, t, sub, 1, u00, u01, u10, u11); __syncthreads();
  U3L(45); gatec(psi, t, sub, 0, 1, u00, u01, u10, u11); __syncthreads();
  U3L(48); gate1q(psi, t, sub, 0, u00, u01, u10, u11); __syncthreads();
  U3L(51); gate1q(psi, t, sub, 1, u00, u01, u10, u11); __syncthreads();

  // A00 = <e0| U^H D U |e0> (zero-norm-row fallback), from psi column 0
  if (tid < 64) {
    float2 v = psi[tid * 64];
    float term = (v.x * v.x + v.y * v.y) * (tid < 32 ? 1.f : -1.f);
#pragma unroll
    for (int m = 1; m < 64; m <<= 1) term += __shfl_xor(term, m, 64);
    if (tid == 0) sA00 = term;
  }
  // Build P (128x64 real, bf16): rows [ReU i<32 | ImU i<32 | ReU i>=32 | ImU i>=32]
  for (int idx = tid; idx < 8192; idx += 256) {
    int r = idx >> 6, j = idx & 63;
    int i = (r < 32) ? r : (r < 96) ? (r - 32) : (r - 64);
    bool im = (r >= 32 && r < 64) || (r >= 96);
    float2 v = psi[i * 64 + j];
    Plds[idx] = f2bf(im ? v.y : v.x);
  }
  __syncthreads();

  // ---------- hoist B fragments to registers ----------
  const int lane = tid & 63, wid = sub;
  const int g = lane >> 4, c0 = lane & 15;
  // B[k][n] = P[n + 16*nt][k], n = lane&15, k = 8*(lane>>4)+i (+32*ks)
  const unsigned short* pb = Plds + c0 * 64 + g * 8;
  bf16x8 Bf[8][2];
#pragma unroll
  for (int nt = 0; nt < 8; ++nt) {
    Bf[nt][0] = *(const bf16x8*)(pb + nt * 1024);
    Bf[nt][1] = *(const bf16x8*)(pb + nt * 1024 + 32);
  }
  const float A00 = sA00;

  // ---------- streaming main loop: 64 tiles/block, 16/wave, double-buffered ----------
  const int tile0 = blockIdx.x * 64 + wid * 16;
  const float* fp = F + (size_t)(tile0 * 16 + c0) * 64 + g * 8;

#define LOADT(i, V0, V1, V2, V3) { const float* q_ = fp + (size_t)(i) * 1024; \
    V0 = *(const float4*)(q_); V1 = *(const float4*)(q_ + 4); \
    V2 = *(const float4*)(q_ + 32); V3 = *(const float4*)(q_ + 36); }

#define PROCESS(i, V0, V1, V2, V3) { \
    bf16x8 a0, a1; \
    a0[0] = f2bf(V0.x); a0[1] = f2bf(V0.y); a0[2] = f2bf(V0.z); a0[3] = f2bf(V0.w); \
    a0[4] = f2bf(V1.x); a0[5] = f2bf(V1.y); a0[6] = f2bf(V1.z); a0[7] = f2bf(V1.w); \
    a1[0] = f2bf(V2.x); a1[1] = f2bf(V2.y); a1[2] = f2bf(V2.z); a1[3] = f2bf(V2.w); \
    a1[4] = f2bf(V3.x); a1[5] = f2bf(V3.y); a1[6] = f2bf(V3.z); a1[7] = f2bf(V3.w); \
    f32x4 acc[8]; \
    _Pragma("unroll") \
    for (int nt = 0; nt < 8; ++nt) { \
      acc[nt] = (f32x4){0.f, 0.f, 0.f, 0.f}; \
      acc[nt] = MFMA(a0, Bf[nt][0], acc[nt]); \
      acc[nt] = MFMA(a1, Bf[nt][1], acc[nt]); \
    } \
    float s1[4] = {0, 0, 0, 0}, s2[4] = {0, 0, 0, 0}; \
    _Pragma("unroll") \
    for (int nt = 0; nt < 4; ++nt) { \
      _Pragma("unroll") \
      for (int r = 0; r < 4; ++r) { \
        s1[r] = fmaf(acc[nt][r], acc[nt][r], s1[r]); \
        s2[r] = fmaf(acc[nt + 4][r], acc[nt + 4][r], s2[r]); \
      } \
    } \
    _Pragma("unroll") \
    for (int m = 1; m < 16; m <<= 1) { \
      _Pragma("unroll") \
      for (int r = 0; r < 4; ++r) { \
        s1[r] += __shfl_xor(s1[r], m, 64); \
        s2[r] += __shfl_xor(s2[r], m, 64); \
      } \
    } \
    if (c0 < 4) { \
      float sp_ = (c0 == 0) ? s1[0] : (c0 == 1) ? s1[1] : (c0 == 2) ? s1[2] : s1[3]; \
      float sm_ = (c0 == 0) ? s2[0] : (c0 == 1) ? s2[1] : (c0 == 2) ? s2[2] : s2[3]; \
      float den = sp_ + sm_; \
      out[(size_t)(tile0 + (i)) * 16 + 4 * g + c0] = (den < 1e-30f) ? A00 : (sp_ - sm_) / den; \
    } }

  float4 x0, x1, x2, x3, y0, y1, y2, y3;
  LOADT(0, x0, x1, x2, x3);
#pragma unroll
  for (int i = 0; i < 16; i += 2) {
    LOADT(i + 1, y0, y1, y2, y3);
    PROCESS(i, x0, x1, x2, x3);
    if (i + 2 < 16) LOADT(i + 2, x0, x1, x2, x3);
    PROCESS(i + 1, y0, y1, y2, y3);
  }
#undef LOADT
#undef PROCESS
}

extern "C" void kernel_launch(void* const* d_in, const int* in_sizes, int n_in,
                              void* d_out, int out_size, void* d_ws, size_t ws_size,
                              hipStream_t stream) {
  const float* F = (const float*)d_in[0]; // (262144, 64) fp32
  const float* P = (const float*)d_in[1]; // (54,) fp32
  float* out = (float*)d_out;             // (262144,) fp32
  qfused<<<256, 256, 0, stream>>>(F, P, out);
}

// Round 4
// 114.261 us; speedup vs baseline: 1.3385x; 1.0506x over previous
//
#include <hip/hip_runtime.h>

using f32x4  = __attribute__((ext_vector_type(4))) float;
using bf16x8 = __attribute__((ext_vector_type(8))) short;

__device__ inline unsigned short f2bf(float x) { // fp32 -> bf16 RNE
  unsigned u = __builtin_bit_cast(unsigned, x);
  return (unsigned short)((u + 0x7FFFu + ((u >> 16) & 1u)) >> 16);
}
__device__ inline float2 cmul(float2 a, float2 b) {
  return make_float2(a.x * b.x - a.y * b.y, a.x * b.y + a.y * b.x);
}
__device__ inline float2 cadd(float2 a, float2 b) { return make_float2(a.x + b.x, a.y + b.y); }

// ---- gate helpers on LDS psi[i*64 + t] (i = amplitude, t = basis column) ----
__device__ inline void gate1q(float2* psi, int t, int sub, int q,
                              float2 u00, float2 u01, float2 u10, float2 u11) {
  const int bit = 1 << q, mask = bit - 1;
#pragma unroll
  for (int pp = 0; pp < 8; ++pp) {
    int p  = sub * 8 + pp;
    int i0 = ((p & ~mask) << 1) | (p & mask);
    int i1 = i0 | bit;
    float2 a0 = psi[i0 * 64 + t], a1 = psi[i1 * 64 + t];
    psi[i0 * 64 + t] = cadd(cmul(u00, a0), cmul(u01, a1));
    psi[i1 * 64 + t] = cadd(cmul(u10, a0), cmul(u11, a1));
  }
}

__device__ inline void gatec(float2* psi, int t, int sub, int c, int g,
                             float2 v00, float2 v01, float2 v10, float2 v11) {
  const int cb = 1 << c, gb = 1 << g;
  const int lo = (c < g ? c : g), hi = (c < g ? g : c);
  const int mlo = (1 << lo) - 1, mhi = (1 << hi) - 1;
#pragma unroll
  for (int pp = 0; pp < 4; ++pp) {
    int p = sub * 4 + pp;
    int y = ((p & ~mlo) << 1) | (p & mlo);
    y     = ((y & ~mhi) << 1) | (y & mhi);
    int i0 = y | cb;
    int i1 = i0 | gb;
    float2 a0 = psi[i0 * 64 + t], a1 = psi[i1 * 64 + t];
    psi[i0 * 64 + t] = cadd(cmul(v00, a0), cmul(v01, a1));
    psi[i1 * 64 + t] = cadd(cmul(v10, a0), cmul(v11, a1));
  }
}

#define MFMA(A, B, C) __builtin_amdgcn_mfma_f32_16x16x32_bf16(A, B, C, 0, 0, 0)

// Fused: every block simulates the 64x64 circuit unitary in LDS, builds the
// real 128x64 matrix P = [ReU(i<32); ImU(i<32); ReU(i>=32); ImU(i>=32)] in
// bf16, hoists its MFMA fragments to registers (P is the A-operand), then
// streams F as the B-operand:
//   out = (|Pp f|^2 - |Pm f|^2) / (|Pp f|^2 + |Pm f|^2)   (den free: U unitary)
// C-layout row = P-row -> the norm-reduce is in-lane + 2 shfl_xor levels.
// grid=768 (3 blocks/CU, LDS 49KB): 12 waves/CU for HBM latency hiding.
__global__ __launch_bounds__(256, 3) void qfused(const float* __restrict__ F,
                                                 const float* __restrict__ Pp,
                                                 float* __restrict__ out) {
  __shared__ float2 psi[64 * 64];                                        // 32 KB
  __shared__ __attribute__((aligned(16))) unsigned short Plds[128 * 64]; // 16 KB
  __shared__ float tS[54], tC[54], tSh[54], tCh[54];
  __shared__ float sA00;

  const int tid = threadIdx.x;
  const int t = tid & 63, sub = tid >> 6;

  // ---------- prologue: trig tables + circuit sim (verified r1-r3) ----------
  if (tid < 54) {
    float p = Pp[tid];
    tS[tid]  = __sinf(p);
    tC[tid]  = __cosf(p);
    tSh[tid] = __sinf(0.5f * p);
    tCh[tid] = __cosf(0.5f * p);
  }
  for (int idx = tid; idx < 4096; idx += 256)
    psi[idx] = make_float2(((idx >> 6) == (idx & 63)) ? 1.f : 0.f, 0.f);
  __syncthreads();

  float2 u00, u01, u10, u11;
  const float2 Z = make_float2(0.f, 0.f), ONE = make_float2(1.f, 0.f);
  auto U3L = [&](int i) {
    float ch = tCh[i], sh = tSh[i];
    float cp = tC[i + 1], sp = tS[i + 1];
    float cl = tC[i + 2], sl = tS[i + 2];
    u00 = make_float2(ch, 0.f);
    u01 = make_float2(-cl * sh, -sl * sh);
    u10 = make_float2(cp * sh, sp * sh);
    u11 = make_float2((cp * cl - sp * sl) * ch, (cp * sl + sp * cl) * ch);
  };
  auto PH = [&](int i) { return make_float2(tC[i], tS[i]); };

#pragma unroll
  for (int q = 0; q < 6; ++q) {
    U3L(3 * q); gate1q(psi, t, sub, q, u00, u01, u10, u11); __syncthreads();
  }
  gatec(psi, t, sub, 2, 1, Z, ONE, ONE, Z); __syncthreads();
  gate1q(psi, t, sub, 1, ONE, Z, Z, PH(18)); __syncthreads();
  gatec(psi, t, sub, 4, 3, Z, ONE, ONE, Z); __syncthreads();
  gate1q(psi, t, sub, 3, ONE, Z, Z, PH(19)); __syncthreads();
  const int qs[4] = {0, 1, 3, 5};
#pragma unroll
  for (int ii = 0; ii < 4; ++ii) {
    U3L(20 + 3 * ii); gate1q(psi, t, sub, qs[ii], u00, u01, u10, u11); __syncthreads();
  }
  U3L(32); gatec(psi, t, sub, 0, 1, u00, u01, u10, u11); __syncthreads();
  U3L(35); gatec(psi, t, sub, 3, 5, u00, u01, u10, u11); __syncthreads();
  gatec(psi, t, sub, 3, 1, Z, ONE, ONE, Z); __syncthreads();
  gate1q(psi, t, sub, 1, ONE, Z, Z, PH(38)); __syncthreads();
  U3L(39); gate1q(psi, t, sub, 0, u00, u01, u10, u11); __syncthreads();
  U3L(42); gate1q(psi, t, sub, 1, u00, u01, u10, u11); __syncthreads();
  U3L(45); gatec(psi, t, sub, 0, 1, u00, u01, u10, u11); __syncthreads();
  U3L(48); gate1q(psi, t, sub, 0, u00, u01, u10, u11); __syncthreads();
  U3L(51); gate1q(psi, t, sub, 1, u00, u01, u10, u11); __syncthreads();

  // A00 = <e0| U^H D U |e0> (zero-norm-row fallback), from psi column 0
  if (tid < 64) {
    float2 v = psi[tid * 64];
    float term = (v.x * v.x + v.y * v.y) * (tid < 32 ? 1.f : -1.f);
#pragma unroll
    for (int m = 1; m < 64; m <<= 1) term += __shfl_xor(term, m, 64);
    if (tid == 0) sA00 = term;
  }
  // P (128x64 real, bf16): rows [ReU i<32 | ImU i<32 | ReU i>=32 | ImU i>=32]
  for (int idx = tid; idx < 8192; idx += 256) {
    int r = idx >> 6, j = idx & 63;
    int i = (r < 32) ? r : (r < 96) ? (r - 32) : (r - 64);
    bool im = (r >= 32 && r < 64) || (r >= 96);
    float2 v = psi[i * 64 + j];
    Plds[idx] = f2bf(im ? v.y : v.x);
  }
  __syncthreads();

  // ---------- hoist P fragments (A-operand) to registers ----------
  const int lane = tid & 63, wid = sub;
  const int g = lane >> 4, c0 = lane & 15;
  // A[m][k] = P[16*mt + m][k], m = lane&15, k = 8*(lane>>4)+i (+32*ks)
  const unsigned short* pb = Plds + c0 * 64 + g * 8;
  bf16x8 Bf[8][2];
#pragma unroll
  for (int mt = 0; mt < 8; ++mt) {
    Bf[mt][0] = *(const bf16x8*)(pb + mt * 1024);
    Bf[mt][1] = *(const bf16x8*)(pb + mt * 1024 + 32);
  }
  const float A00 = sA00;

  // ---------- streaming: 3072 waves, 5-6 contiguous tiles each ----------
  const int gid   = (int)blockIdx.x * 4 + wid;          // 0..3071
  const int start = gid * 5 + (gid < 1024 ? gid : 1024);
  const int count = 5 + (gid < 1024 ? 1 : 0);
  // B[k][n] = F[b0 + n][k]: n = lane&15 = c0, k = 8*g + i (+32*ks)
  const float* fp = F + (size_t)start * 1024 + (size_t)c0 * 64 + g * 8;

#define LOADT(i, V0, V1, V2, V3) { const float* q_ = fp + (size_t)(i) * 1024; \
    V0 = *(const float4*)(q_); V1 = *(const float4*)(q_ + 4); \
    V2 = *(const float4*)(q_ + 32); V3 = *(const float4*)(q_ + 36); }

#define PROCESS(i, V0, V1, V2, V3) { \
    bf16x8 a0, a1; \
    a0[0] = f2bf(V0.x); a0[1] = f2bf(V0.y); a0[2] = f2bf(V0.z); a0[3] = f2bf(V0.w); \
    a0[4] = f2bf(V1.x); a0[5] = f2bf(V1.y); a0[6] = f2bf(V1.z); a0[7] = f2bf(V1.w); \
    a1[0] = f2bf(V2.x); a1[1] = f2bf(V2.y); a1[2] = f2bf(V2.z); a1[3] = f2bf(V2.w); \
    a1[4] = f2bf(V3.x); a1[5] = f2bf(V3.y); a1[6] = f2bf(V3.z); a1[7] = f2bf(V3.w); \
    f32x4 acc[8]; \
    _Pragma("unroll") \
    for (int mt = 0; mt < 8; ++mt) { \
      acc[mt] = (f32x4){0.f, 0.f, 0.f, 0.f}; \
      acc[mt] = MFMA(Bf[mt][0], a0, acc[mt]); \
      acc[mt] = MFMA(Bf[mt][1], a1, acc[mt]); \
    } \
    float sp_ = 0.f, sm_ = 0.f; \
    _Pragma("unroll") \
    for (int mt = 0; mt < 4; ++mt) { \
      _Pragma("unroll") \
      for (int r = 0; r < 4; ++r) { \
        sp_ = fmaf(acc[mt][r], acc[mt][r], sp_); \
        sm_ = fmaf(acc[mt + 4][r], acc[mt + 4][r], sm_); \
      } \
    } \
    sp_ += __shfl_xor(sp_, 16, 64); sm_ += __shfl_xor(sm_, 16, 64); \
    sp_ += __shfl_xor(sp_, 32, 64); sm_ += __shfl_xor(sm_, 32, 64); \
    if (lane < 16) { \
      float den = sp_ + sm_; \
      out[(size_t)(start + (i)) * 16 + c0] = (den < 1e-30f) ? A00 : (sp_ - sm_) / den; \
    } }

  float4 x0, x1, x2, x3, y0, y1, y2, y3;
  LOADT(0, x0, x1, x2, x3);
#pragma unroll
  for (int i = 0; i < 6; i += 2) {
    if (i >= count) break;
    const bool has2 = (i + 1 < count);
    if (has2) LOADT(i + 1, y0, y1, y2, y3);
    PROCESS(i, x0, x1, x2, x3);
    if (i + 2 < count) LOADT(i + 2, x0, x1, x2, x3);
    if (has2) PROCESS(i + 1, y0, y1, y2, y3);
  }
#undef LOADT
#undef PROCESS
}

extern "C" void kernel_launch(void* const* d_in, const int* in_sizes, int n_in,
                              void* d_out, int out_size, void* d_ws, size_t ws_size,
                              hipStream_t stream) {
  const float* F = (const float*)d_in[0]; // (262144, 64) fp32
  const float* P = (const float*)d_in[1]; // (54,) fp32
  float* out = (float*)d_out;             // (262144,) fp32
  qfused<<<768, 256, 0, stream>>>(F, P, out);
}

// Round 5
// 112.939 us; speedup vs baseline: 1.3541x; 1.0117x over previous
//
#include <hip/hip_runtime.h>

using f32x4  = __attribute__((ext_vector_type(4))) float;
using bf16x8 = __attribute__((ext_vector_type(8))) short;

// Device-global handoff sim -> stream; rewritten every call before use.
__device__ __attribute__((aligned(16))) unsigned short g_P[128 * 64]; // bf16 [ReU+;ImU+;ReU-;ImU-]
__device__ float g_A00;

__device__ inline unsigned short f2bf(float x) { // fp32 -> bf16 RNE
  unsigned u = __builtin_bit_cast(unsigned, x);
  return (unsigned short)((u + 0x7FFFu + ((u >> 16) & 1u)) >> 16);
}
__device__ inline float2 cmul(float2 x, float2 y) {
  return make_float2(x.x * y.x - x.y * y.y, x.x * y.y + x.y * y.x);
}
__device__ inline float2 cfma(float2 x, float2 y, float2 a) { // a + x*y
  return make_float2(fmaf(x.x, y.x, fmaf(-x.y, y.y, a.x)),
                     fmaf(x.x, y.y, fmaf(x.y, y.x, a.y)));
}

struct u2 { float2 a, b, c, d; };  // 2x2 complex [[a,b],[c,d]]
struct c4 { float2 m[4][4]; };     // 4x4 complex; constant-indexed only (rule #20)

__device__ inline u2 mk3(const float* tS, const float* tC,
                         const float* tSh, const float* tCh, int i) {
  float ch = tCh[i], sh = tSh[i];
  float cp = tC[i + 1], sp = tS[i + 1];
  float cl = tC[i + 2], sl = tS[i + 2];
  u2 r;
  r.a = make_float2(ch, 0.f);
  r.b = make_float2(-cl * sh, -sl * sh);
  r.c = make_float2(cp * sh, sp * sh);
  r.d = make_float2((cp * cl - sp * sl) * ch, (cp * sl + sp * cl) * ch);
  return r;
}
__device__ inline c4 kron2(const u2& A, const u2& B) { // A on high bit (qa)
  c4 r;
  r.m[0][0]=cmul(A.a,B.a); r.m[0][1]=cmul(A.a,B.b); r.m[0][2]=cmul(A.b,B.a); r.m[0][3]=cmul(A.b,B.b);
  r.m[1][0]=cmul(A.a,B.c); r.m[1][1]=cmul(A.a,B.d); r.m[1][2]=cmul(A.b,B.c); r.m[1][3]=cmul(A.b,B.d);
  r.m[2][0]=cmul(A.c,B.a); r.m[2][1]=cmul(A.c,B.b); r.m[2][2]=cmul(A.d,B.a); r.m[2][3]=cmul(A.d,B.b);
  r.m[3][0]=cmul(A.c,B.c); r.m[3][1]=cmul(A.c,B.d); r.m[3][2]=cmul(A.d,B.c); r.m[3][3]=cmul(A.d,B.d);
  return r;
}
__device__ inline c4 mul4(const c4& X, const c4& Y) { // X*Y (X applied after Y)
  c4 r;
#pragma unroll
  for (int i = 0; i < 4; ++i)
#pragma unroll
    for (int j = 0; j < 4; ++j) {
      float2 s = make_float2(0.f, 0.f);
#pragma unroll
      for (int k = 0; k < 4; ++k) s = cfma(X.m[i][k], Y.m[k][j], s);
      r.m[i][j] = s;
    }
  return r;
}
__device__ inline c4 cu4(const u2& U) { // controlled-U, control = high bit
  c4 r;
#pragma unroll
  for (int i = 0; i < 4; ++i)
#pragma unroll
    for (int j = 0; j < 4; ++j) r.m[i][j] = make_float2(0.f, 0.f);
  r.m[0][0] = r.m[1][1] = make_float2(1.f, 0.f);
  r.m[2][2] = U.a; r.m[2][3] = U.b; r.m[3][2] = U.c; r.m[3][3] = U.d;
  return r;
}
__device__ inline c4 gcxp(float2 e) { // P(lam on target=low) * CX(ctrl=high)
  c4 r;
#pragma unroll
  for (int i = 0; i < 4; ++i)
#pragma unroll
    for (int j = 0; j < 4; ++j) r.m[i][j] = make_float2(0.f, 0.f);
  r.m[0][0] = make_float2(1.f, 0.f); r.m[1][1] = e;
  r.m[2][3] = make_float2(1.f, 0.f); r.m[3][2] = e;
  return r;
}

// general 4x4 on (qa=high, qb=low); psi[i*64+t], 16 quads split over sub=0..3
__device__ inline void g2q(float2* psi, int t, int sub, int qa, int qb, const c4& G) {
  const int lo = qa < qb ? qa : qb, hi = qa < qb ? qb : qa;
  const int mlo = (1 << lo) - 1, mhi = (1 << hi) - 1;
  const int dA = (1 << qa) * 64, dB = (1 << qb) * 64;
#pragma unroll
  for (int pp = 0; pp < 4; ++pp) {
    int p = sub * 4 + pp;
    int y = ((p & ~mlo) << 1) | (p & mlo);
    y     = ((y & ~mhi) << 1) | (y & mhi);
    int ad = y * 64 + t;
    float2 a0 = psi[ad], a1 = psi[ad + dB], a2 = psi[ad + dA], a3 = psi[ad + dA + dB];
    float2 o0 = cfma(G.m[0][3], a3, cfma(G.m[0][2], a2, cfma(G.m[0][1], a1, cmul(G.m[0][0], a0))));
    float2 o1 = cfma(G.m[1][3], a3, cfma(G.m[1][2], a2, cfma(G.m[1][1], a1, cmul(G.m[1][0], a0))));
    float2 o2 = cfma(G.m[2][3], a3, cfma(G.m[2][2], a2, cfma(G.m[2][1], a1, cmul(G.m[2][0], a0))));
    float2 o3 = cfma(G.m[3][3], a3, cfma(G.m[3][2], a2, cfma(G.m[3][1], a1, cmul(G.m[3][0], a0))));
    psi[ad] = o0; psi[ad + dB] = o1; psi[ad + dA] = o2; psi[ad + dA + dB] = o3;
  }
}
__device__ inline float2 pick(const u2& U, int bi, int bt) {
  return bi ? (bt ? U.d : U.c) : (bt ? U.b : U.a);
}

// ---- sim: 1 block. 7 LDS stages (was 20): layer1 = direct tensor product;
// remaining gates composed in-register into six 4x4s on qubit pairs. ----
__global__ __launch_bounds__(256) void sim_kernel(const float* __restrict__ Pp) {
  __shared__ float2 psi[64 * 64];
  __shared__ float tS[54], tC[54], tSh[54], tCh[54];
  const int tid = threadIdx.x, t = tid & 63, sub = tid >> 6;
  if (tid < 54) {
    float p = Pp[tid];
    tS[tid] = __sinf(p);  tC[tid] = __cosf(p);
    tSh[tid] = __sinf(0.5f * p); tCh[tid] = __cosf(0.5f * p);
  }
  __syncthreads();

  // stage 1: psi[i][t] = prod_q Uq[i_q][t_q]  (input = identity columns)
  {
    u2 L0 = mk3(tS, tC, tSh, tCh, 0),  L1 = mk3(tS, tC, tSh, tCh, 3);
    u2 L2 = mk3(tS, tC, tSh, tCh, 6),  L3 = mk3(tS, tC, tSh, tCh, 9);
    u2 L4 = mk3(tS, tC, tSh, tCh, 12), L5 = mk3(tS, tC, tSh, tCh, 15);
#pragma unroll
    for (int e = 0; e < 16; ++e) {
      int idx = tid + 256 * e;        // idx = i*64 + tt
      int i = idx >> 6, tt = idx & 63;
      float2 f = pick(L0, i & 1, tt & 1);
      f = cmul(f, pick(L1, (i >> 1) & 1, (tt >> 1) & 1));
      f = cmul(f, pick(L2, (i >> 2) & 1, (tt >> 2) & 1));
      f = cmul(f, pick(L3, (i >> 3) & 1, (tt >> 3) & 1));
      f = cmul(f, pick(L4, (i >> 4) & 1, (tt >> 4) & 1));
      f = cmul(f, pick(L5, (i >> 5) & 1, (tt >> 5) & 1));
      psi[idx] = f;
    }
  }
  __syncthreads();
  auto E = [&](int i) { return make_float2(tC[i], tS[i]); };
  { c4 G = gcxp(E(18)); g2q(psi, t, sub, 2, 1, G); } __syncthreads();  // CX(2,1);P18(1)
  { c4 G = gcxp(E(19)); g2q(psi, t, sub, 4, 3, G); } __syncthreads();  // CX(4,3);P19(3)
  { c4 G = mul4(cu4(mk3(tS, tC, tSh, tCh, 32)),                        // U20(0),U23(1);CU32(0->1)
                kron2(mk3(tS, tC, tSh, tCh, 20), mk3(tS, tC, tSh, tCh, 23)));
    g2q(psi, t, sub, 0, 1, G); } __syncthreads();
  { c4 G = mul4(cu4(mk3(tS, tC, tSh, tCh, 35)),                        // U26(3),U29(5);CU35(3->5)
                kron2(mk3(tS, tC, tSh, tCh, 26), mk3(tS, tC, tSh, tCh, 29)));
    g2q(psi, t, sub, 3, 5, G); } __syncthreads();
  { c4 G = gcxp(E(38)); g2q(psi, t, sub, 3, 1, G); } __syncthreads();  // CX(3,1);P38(1)
  { c4 G = mul4(kron2(mk3(tS, tC, tSh, tCh, 48), mk3(tS, tC, tSh, tCh, 51)),
                mul4(cu4(mk3(tS, tC, tSh, tCh, 45)),                   // U39,U42;CU45;U48,U51
                     kron2(mk3(tS, tC, tSh, tCh, 39), mk3(tS, tC, tSh, tCh, 42))));
    g2q(psi, t, sub, 0, 1, G); } __syncthreads();

  // A00 = <e0|U^H D U|e0> from column 0 (zero-norm fallback)
  if (tid < 64) {
    float2 v = psi[tid * 64];
    float term = (v.x * v.x + v.y * v.y) * (tid < 32 ? 1.f : -1.f);
#pragma unroll
    for (int m = 1; m < 64; m <<= 1) term += __shfl_xor(term, m, 64);
    if (tid == 0) g_A00 = term;
  }
  // P (128x64 bf16): rows [ReU i<32 | ImU i<32 | ReU i>=32 | ImU i>=32]
  for (int idx = tid; idx < 8192; idx += 256) {
    int r = idx >> 6, j = idx & 63;
    int i = (r < 32) ? r : (r < 96) ? (r - 32) : (r - 64);
    bool im = (r >= 32 && r < 64) || (r >= 96);
    float2 v = psi[i * 64 + j];
    g_P[idx] = f2bf(im ? v.y : v.x);
  }
}

#define MFMA(A, B, C) __builtin_amdgcn_mfma_f32_16x16x32_bf16(A, B, C, 0, 0, 0)

// ---- stream: no LDS, P fragments hoisted from global (L2 broadcast).
// out = (|Pp f|^2 - |Pm f|^2) / (|Pp f|^2 + |Pm f|^2); den free (U unitary). ----
__global__ __launch_bounds__(256, 3) void qexp(const float* __restrict__ F,
                                               float* __restrict__ out) {
  const int tid = threadIdx.x;
  const int lane = tid & 63, wid = tid >> 6;
  const int g = lane >> 4, c0 = lane & 15;

  // A[m][k] = P[16*mt + m][k], m = lane&15, k = 8*(lane>>4)+i (+32*ks)
  const unsigned short* pb = g_P + c0 * 64 + g * 8;
  bf16x8 Bf[8][2];
#pragma unroll
  for (int mt = 0; mt < 8; ++mt) {
    Bf[mt][0] = *(const bf16x8*)(pb + mt * 1024);
    Bf[mt][1] = *(const bf16x8*)(pb + mt * 1024 + 32);
  }
  const float A00 = g_A00;

  // 3072 waves, 5-6 contiguous tiles each (16384 tiles of 16 rows)
  const int gid   = (int)blockIdx.x * 4 + wid;
  const int start = gid * 5 + (gid < 1024 ? gid : 1024);
  const int count = 5 + (gid < 1024 ? 1 : 0);
  // B[k][n] = F[row0 + n][k]: n = c0, k = 8*g + i (+32*ks)
  const float* fp = F + (size_t)start * 1024 + (size_t)c0 * 64 + g * 8;

#define LOADT(i, V0, V1, V2, V3) { const float* q_ = fp + (size_t)(i) * 1024; \
    V0 = *(const float4*)(q_); V1 = *(const float4*)(q_ + 4); \
    V2 = *(const float4*)(q_ + 32); V3 = *(const float4*)(q_ + 36); }

#define PROCESS(i, V0, V1, V2, V3) { \
    bf16x8 a0, a1; \
    a0[0] = f2bf(V0.x); a0[1] = f2bf(V0.y); a0[2] = f2bf(V0.z); a0[3] = f2bf(V0.w); \
    a0[4] = f2bf(V1.x); a0[5] = f2bf(V1.y); a0[6] = f2bf(V1.z); a0[7] = f2bf(V1.w); \
    a1[0] = f2bf(V2.x); a1[1] = f2bf(V2.y); a1[2] = f2bf(V2.z); a1[3] = f2bf(V2.w); \
    a1[4] = f2bf(V3.x); a1[5] = f2bf(V3.y); a1[6] = f2bf(V3.z); a1[7] = f2bf(V3.w); \
    f32x4 acc[8]; \
    _Pragma("unroll") \
    for (int mt = 0; mt < 8; ++mt) { \
      acc[mt] = (f32x4){0.f, 0.f, 0.f, 0.f}; \
      acc[mt] = MFMA(Bf[mt][0], a0, acc[mt]); \
      acc[mt] = MFMA(Bf[mt][1], a1, acc[mt]); \
    } \
    float sp_ = 0.f, sm_ = 0.f; \
    _Pragma("unroll") \
    for (int mt = 0; mt < 4; ++mt) { \
      _Pragma("unroll") \
      for (int r = 0; r < 4; ++r) { \
        sp_ = fmaf(acc[mt][r], acc[mt][r], sp_); \
        sm_ = fmaf(acc[mt + 4][r], acc[mt + 4][r], sm_); \
      } \
    } \
    sp_ += __shfl_xor(sp_, 16, 64); sm_ += __shfl_xor(sm_, 16, 64); \
    sp_ += __shfl_xor(sp_, 32, 64); sm_ += __shfl_xor(sm_, 32, 64); \
    if (lane < 16) { \
      float den = sp_ + sm_; \
      out[(size_t)(start + (i)) * 16 + c0] = (den < 1e-30f) ? A00 : (sp_ - sm_) / den; \
    } }

  float4 x0, x1, x2, x3, y0, y1, y2, y3;
  LOADT(0, x0, x1, x2, x3);
#pragma unroll
  for (int i = 0; i < 6; i += 2) {
    if (i >= count) break;
    const bool has2 = (i + 1 < count);
    if (has2) LOADT(i + 1, y0, y1, y2, y3);
    PROCESS(i, x0, x1, x2, x3);
    if (i + 2 < count) LOADT(i + 2, x0, x1, x2, x3);
    if (has2) PROCESS(i + 1, y0, y1, y2, y3);
  }
#undef LOADT
#undef PROCESS
}

extern "C" void kernel_launch(void* const* d_in, const int* in_sizes, int n_in,
                              void* d_out, int out_size, void* d_ws, size_t ws_size,
                              hipStream_t stream) {
  const float* F = (const float*)d_in[0]; // (262144, 64) fp32
  const float* P = (const float*)d_in[1]; // (54,) fp32
  float* out = (float*)d_out;             // (262144,) fp32
  sim_kernel<<<1, 256, 0, stream>>>(P);
  qexp<<<768, 256, 0, stream>>>(F, out);
}